// Round 2
// baseline (58.182 us; speedup 1.0000x reference)
//
#include <hip/hip_runtime.h>

#define IMH 512
#define IMW 512
#define BATCH 8
#define NTOK 20480
#define NC 4096
#define NF 16384
#define ED 128

// ---------------- Kernel 1: fused coarse embed + Sobel edge map ------------
// blocks [0,2048): coarse, 16 patches/block, 256 threads
// blocks [2048,2560): edge, 64x64 pixel tile -> 16x16 pooled cells (fp64)
__global__ __launch_bounds__(256) void fused_edge_coarse(const float* __restrict__ x,
                                                         const float* __restrict__ wc,
                                                         const float* __restrict__ bc,
                                                         const float* __restrict__ temb,
                                                         float* __restrict__ out,
                                                         double* __restrict__ edges) {
    __shared__ union {
        float esm[66][68];
        struct { float smc[8][128]; float smo[16][128]; } c;
    } U;
    int blk = blockIdx.x;
    int t = threadIdx.x;
    if (blk < 2048) {
        // ---- coarse role ----
        int b = blk >> 8;
        int p0 = (blk & 255) * 16;     // first of 16 patches, same patch-row
        int hp = p0 >> 6;
        int wp0 = p0 & 63;
        int d = t & 127;
        int h = t >> 7;                // 0/1: patches 0-7 vs 8-15
        float wcol[64];
        #pragma unroll
        for (int k = 0; k < 64; ++k) wcol[k] = wc[k * ED + d];
        const float* img = x + ((size_t)b * IMH + hp * 8) * IMW + wp0 * 8;
        {
            int r = t >> 5, c4 = t & 31;   // 8 rows x 32 float4
            *(float4*)&U.c.smc[r][c4 * 4] = *(const float4*)&img[r * IMW + c4 * 4];
        }
        __syncthreads();
        float base = bc[d] + temb[d];
        float accs[8];
        #pragma unroll
        for (int p = 0; p < 8; ++p) {
            int col0 = h * 64 + p * 8;
            float acc = base;
            #pragma unroll
            for (int r = 0; r < 8; ++r) {
                float4 v0 = *(const float4*)&U.c.smc[r][col0];
                float4 v1 = *(const float4*)&U.c.smc[r][col0 + 4];
                acc += v0.x * wcol[r * 8 + 0] + v0.y * wcol[r * 8 + 1]
                     + v0.z * wcol[r * 8 + 2] + v0.w * wcol[r * 8 + 3]
                     + v1.x * wcol[r * 8 + 4] + v1.y * wcol[r * 8 + 5]
                     + v1.z * wcol[r * 8 + 6] + v1.w * wcol[r * 8 + 7];
            }
            accs[p] = acc;
        }
        #pragma unroll
        for (int p = 0; p < 8; ++p) U.c.smo[h * 8 + p][d] = accs[p];
        __syncthreads();
        float* dst = out + ((size_t)b * NTOK + p0) * ED;   // 16*128 contiguous floats
        const float* so = (const float*)U.c.smo;
        #pragma unroll
        for (int j = 0; j < 2; ++j) {
            int i = t + 256 * j;                            // float4 index 0..511
            *(float4*)&dst[i * 4] = *(const float4*)&so[i * 4];
        }
    } else {
        // ---- edge role (identical math to round-1 passing version) ----
        int blk2 = blk - 2048;
        int b = blk2 >> 6;
        int tile = blk2 & 63;
        int ty0 = (tile >> 3) * 64;
        int tx0 = (tile & 7) * 64;
        const float* img = x + (size_t)b * (IMH * IMW);
        for (int idx = t; idx < 66 * 66; idx += 256) {
            int r = idx / 66, c = idx - r * 66;
            int gy = ty0 - 1 + r, gx = tx0 - 1 + c;
            float v = 0.f;
            if (gy >= 0 && gy < IMH && gx >= 0 && gx < IMW) v = img[gy * IMW + gx];
            U.esm[r][c] = v;
        }
        __syncthreads();
        int cy = t >> 4, cx = t & 15;
        double acc = 0.0;
        #pragma unroll
        for (int dy = 0; dy < 4; ++dy) {
            int py = cy * 4 + dy + 1;
            #pragma unroll
            for (int dx = 0; dx < 4; ++dx) {
                int px = cx * 4 + dx + 1;
                double a00 = (double)U.esm[py - 1][px - 1];
                double a01 = (double)U.esm[py - 1][px];
                double a02 = (double)U.esm[py - 1][px + 1];
                double a10 = (double)U.esm[py][px - 1];
                double a12 = (double)U.esm[py][px + 1];
                double a20 = (double)U.esm[py + 1][px - 1];
                double a21 = (double)U.esm[py + 1][px];
                double a22 = (double)U.esm[py + 1][px + 1];
                double sx = (a02 + 2.0 * a12 + a22) - (a00 + 2.0 * a10 + a20);
                double sy = (a20 + 2.0 * a21 + a22) - (a00 + 2.0 * a01 + a02);
                acc += sqrt(sx * sx + sy * sy);
            }
        }
        int gy = (ty0 >> 2) + cy;
        int gx = (tx0 >> 2) + cx;
        edges[((size_t)b << 14) + gy * 128 + gx] = acc * (1.0 / 16.0);
    }
}

// ---------------- Kernel 2: per-batch mean, mask, prefix scan --------------
// one block per batch, 1024 threads, 16 elements/thread, 2 barriers
__global__ __launch_bounds__(1024) void scan_kernel(const double* __restrict__ edges,
                                                    int* __restrict__ pos,
                                                    int* __restrict__ Karr,
                                                    float* __restrict__ mask_out) {
    int b = blockIdx.x;
    const double* e = edges + ((size_t)b << 14);
    int t = threadIdx.x;
    int lane = t & 63, wid = t >> 6;
    double v[16];
    #pragma unroll
    for (int j = 0; j < 8; ++j) {
        double2 dv = *(const double2*)&e[t * 16 + j * 2];
        v[2 * j] = dv.x; v[2 * j + 1] = dv.y;
    }
    double s = 0.0;
    #pragma unroll
    for (int j = 0; j < 16; ++j) s += v[j];
    #pragma unroll
    for (int off = 32; off > 0; off >>= 1) s += __shfl_xor(s, off);
    __shared__ double wsum[16];
    __shared__ int wcnt[16];
    if (lane == 0) wsum[wid] = s;
    __syncthreads();
    double total = 0.0;
    #pragma unroll
    for (int w = 0; w < 16; ++w) total += wsum[w];
    double mean = total * (1.0 / 16384.0);
    int m[16], cnt = 0;
    #pragma unroll
    for (int j = 0; j < 16; ++j) { m[j] = (v[j] > mean) ? 1 : 0; cnt += m[j]; }
    int incl = cnt;
    #pragma unroll
    for (int off = 1; off < 64; off <<= 1) {
        int up = __shfl_up(incl, off);
        if (lane >= off) incl += up;
    }
    if (lane == 63) wcnt[wid] = incl;
    __syncthreads();
    int woff = 0, Ktot = 0;
    #pragma unroll
    for (int w = 0; w < 16; ++w) { int c = wcnt[w]; Ktot += c; if (w < wid) woff += c; }
    int run = woff + incl - cnt;
    float mf[16]; int pv[16];
    #pragma unroll
    for (int j = 0; j < 16; ++j) {
        pv[j] = m[j] ? run : -1;
        run += m[j];
        mf[j] = m[j] ? 1.0f : 0.0f;
    }
    float* mb = mask_out + ((size_t)b << 14) + t * 16;
    int* pb = pos + ((size_t)b << 14) + t * 16;
    #pragma unroll
    for (int q = 0; q < 4; ++q) {
        *(float4*)&mb[q * 4] = make_float4(mf[4 * q], mf[4 * q + 1], mf[4 * q + 2], mf[4 * q + 3]);
        *(int4*)&pb[q * 4] = make_int4(pv[4 * q], pv[4 * q + 1], pv[4 * q + 2], pv[4 * q + 3]);
    }
    if (t == 0) Karr[b] = Ktot;
}

// ---------------- Kernel 3: fine patch embed + compact scatter + fill ------
// grid (512, 8), 256 threads; 32 fine patches/block; thread = 4 dims of token
__global__ __launch_bounds__(256) void fine_kernel(const float* __restrict__ x,
                                                   const float* __restrict__ wfp,
                                                   const float* __restrict__ bfp,
                                                   const float* __restrict__ temb,
                                                   const int* __restrict__ pos,
                                                   const int* __restrict__ Karr,
                                                   float* __restrict__ out) {
    int b = blockIdx.y;
    int i0 = blockIdx.x * 32;
    int hf = i0 >> 7;
    int wf0 = i0 & 127;
    int t = threadIdx.x;
    int d4 = t & 31;        // float4 lane over dims
    int g = t >> 5;         // 0..7
    __shared__ float smx[4][128];
    float4 wcol[16];
    #pragma unroll
    for (int k = 0; k < 16; ++k) wcol[k] = *(const float4*)&wfp[k * ED + d4 * 4];
    const float* img = x + ((size_t)b * IMH + hf * 4) * IMW + wf0 * 4;
    if (t < 128) {
        int r = t >> 5, c4 = t & 31;
        *(float4*)&smx[r][c4 * 4] = *(const float4*)&img[r * IMW + c4 * 4];
    }
    __syncthreads();
    int K = Karr[b];
    const int* posb = pos + ((size_t)b << 14);
    float4 fill = *(const float4*)&temb[ED + d4 * 4];
    float4 bse = *(const float4*)&bfp[d4 * 4];
    float4 base = make_float4(bse.x + fill.x, bse.y + fill.y, bse.z + fill.z, bse.w + fill.w);
    float4* tok = (float4*)(out + ((size_t)b * NTOK + NC) * ED);
    #pragma unroll
    for (int pp = 0; pp < 4; ++pp) {
        int p = g + pp * 8;
        int i = i0 + p;
        int ps = posb[i];
        if (ps >= 0) {
            float4 acc = base;
            #pragma unroll
            for (int r = 0; r < 4; ++r) {
                float4 vv = *(const float4*)&smx[r][p * 4];
                acc.x += vv.x * wcol[4 * r].x + vv.y * wcol[4 * r + 1].x + vv.z * wcol[4 * r + 2].x + vv.w * wcol[4 * r + 3].x;
                acc.y += vv.x * wcol[4 * r].y + vv.y * wcol[4 * r + 1].y + vv.z * wcol[4 * r + 2].y + vv.w * wcol[4 * r + 3].y;
                acc.z += vv.x * wcol[4 * r].z + vv.y * wcol[4 * r + 1].z + vv.z * wcol[4 * r + 2].z + vv.w * wcol[4 * r + 3].z;
                acc.w += vv.x * wcol[4 * r].w + vv.y * wcol[4 * r + 1].w + vv.z * wcol[4 * r + 2].w + vv.w * wcol[4 * r + 3].w;
            }
            tok[(size_t)ps * 32 + d4] = acc;
        }
        if (i >= K) {
            tok[(size_t)i * 32 + d4] = fill;
        }
    }
}

extern "C" void kernel_launch(void* const* d_in, const int* in_sizes, int n_in,
                              void* d_out, int out_size, void* d_ws, size_t ws_size,
                              hipStream_t stream) {
    const float* x    = (const float*)d_in[0];
    const float* wc   = (const float*)d_in[1];
    const float* bc   = (const float*)d_in[2];
    const float* wfp  = (const float*)d_in[3];
    const float* bfp  = (const float*)d_in[4];
    const float* temb = (const float*)d_in[5];
    float* out = (float*)d_out;

    double* edges = (double*)d_ws;                                  // 1 MiB
    int* pos  = (int*)((char*)d_ws + (size_t)BATCH * NF * sizeof(double));
    int* Karr = (int*)((char*)d_ws + (size_t)BATCH * NF * (sizeof(double) + sizeof(int)));

    float* mask_out = out + (size_t)BATCH * NTOK * ED;

    fused_edge_coarse<<<dim3(2560), 256, 0, stream>>>(x, wc, bc, temb, out, edges);
    scan_kernel<<<dim3(BATCH), 1024, 0, stream>>>(edges, pos, Karr, mask_out);
    fine_kernel<<<dim3(512, BATCH), 256, 0, stream>>>(x, wfp, bfp, temb, pos, Karr, out);
}

// Round 4
// 53.328 us; speedup vs baseline: 1.0910x; 1.0910x over previous
//
#include <hip/hip_runtime.h>

#define IMH 512
#define IMW 512
#define BATCH 8
#define NTOK 20480
#define NC 4096
#define NF 16384
#define ED 128

typedef float vf4 __attribute__((ext_vector_type(4)));
typedef int   vi4 __attribute__((ext_vector_type(4)));

__device__ __forceinline__ void nt_store4(float* p, float a, float b, float c, float d) {
    vf4 v = {a, b, c, d};
    __builtin_nontemporal_store(v, (vf4*)p);
}
__device__ __forceinline__ void nt_store4v(float* p, float4 v) {
    nt_store4(p, v.x, v.y, v.z, v.w);
}

// ---------------- Kernel 1: fused coarse embed + Sobel edge map ------------
// blocks [0,2048): coarse, 16 patches/block, 256 threads, no output staging
// blocks [2048,2560): edge, 64x64 pixel tile -> 16x16 pooled cells (fp64)
__global__ __launch_bounds__(256) void fused_edge_coarse(const float* __restrict__ x,
                                                         const float* __restrict__ wc,
                                                         const float* __restrict__ bc,
                                                         const float* __restrict__ temb,
                                                         float* __restrict__ out,
                                                         double* __restrict__ edges) {
    __shared__ union {
        float esm[66][68];
        float smc[8][128];
    } U;
    int blk = blockIdx.x;
    int t = threadIdx.x;
    if (blk < 2048) {
        // ---- coarse role ----
        int b = blk >> 8;
        int p0 = (blk & 255) * 16;     // first of 16 patches, same patch-row
        int hp = p0 >> 6;
        int wp0 = p0 & 63;
        int d = t & 127;
        int h = t >> 7;                // 0/1: patches 0-7 vs 8-15
        float wcol[64];
        #pragma unroll
        for (int k = 0; k < 64; ++k) wcol[k] = wc[k * ED + d];
        const float* img = x + ((size_t)b * IMH + hp * 8) * IMW + wp0 * 8;
        {
            int r = t >> 5, c4 = t & 31;   // 8 rows x 32 float4
            *(float4*)&U.smc[r][c4 * 4] = *(const float4*)&img[r * IMW + c4 * 4];
        }
        __syncthreads();
        float base = bc[d] + temb[d];
        float* dst = out + ((size_t)b * NTOK + p0 + h * 8) * ED + d;
        #pragma unroll
        for (int p = 0; p < 8; ++p) {
            int col0 = h * 64 + p * 8;
            float acc = base;
            #pragma unroll
            for (int r = 0; r < 8; ++r) {
                float4 v0 = *(const float4*)&U.smc[r][col0];
                float4 v1 = *(const float4*)&U.smc[r][col0 + 4];
                acc += v0.x * wcol[r * 8 + 0] + v0.y * wcol[r * 8 + 1]
                     + v0.z * wcol[r * 8 + 2] + v0.w * wcol[r * 8 + 3]
                     + v1.x * wcol[r * 8 + 4] + v1.y * wcol[r * 8 + 5]
                     + v1.z * wcol[r * 8 + 6] + v1.w * wcol[r * 8 + 7];
            }
            __builtin_nontemporal_store(acc, dst + (size_t)p * ED);
        }
    } else {
        // ---- edge role (identical fp64 math to round-1 passing version) ----
        int blk2 = blk - 2048;
        int b = blk2 >> 6;
        int tile = blk2 & 63;
        int ty0 = (tile >> 3) * 64;
        int tx0 = (tile & 7) * 64;
        const float* img = x + (size_t)b * (IMH * IMW);
        for (int idx = t; idx < 66 * 66; idx += 256) {
            int r = idx / 66, c = idx - r * 66;
            int gy = ty0 - 1 + r, gx = tx0 - 1 + c;
            float v = 0.f;
            if (gy >= 0 && gy < IMH && gx >= 0 && gx < IMW) v = img[gy * IMW + gx];
            U.esm[r][c] = v;
        }
        __syncthreads();
        int cy = t >> 4, cx = t & 15;
        double acc = 0.0;
        #pragma unroll
        for (int dy = 0; dy < 4; ++dy) {
            int py = cy * 4 + dy + 1;
            #pragma unroll
            for (int dx = 0; dx < 4; ++dx) {
                int px = cx * 4 + dx + 1;
                double a00 = (double)U.esm[py - 1][px - 1];
                double a01 = (double)U.esm[py - 1][px];
                double a02 = (double)U.esm[py - 1][px + 1];
                double a10 = (double)U.esm[py][px - 1];
                double a12 = (double)U.esm[py][px + 1];
                double a20 = (double)U.esm[py + 1][px - 1];
                double a21 = (double)U.esm[py + 1][px];
                double a22 = (double)U.esm[py + 1][px + 1];
                double sx = (a02 + 2.0 * a12 + a22) - (a00 + 2.0 * a10 + a20);
                double sy = (a20 + 2.0 * a21 + a22) - (a00 + 2.0 * a01 + a02);
                acc += sqrt(sx * sx + sy * sy);
            }
        }
        int gy = (ty0 >> 2) + cy;
        int gx = (tx0 >> 2) + cx;
        edges[((size_t)b << 14) + gy * 128 + gx] = acc * (1.0 / 16.0);
    }
}

// ---------------- Kernel 2: per-batch mean, mask, prefix scan --------------
// one block per batch, 1024 threads, 16 elements/thread, 2 barriers
__global__ __launch_bounds__(1024) void scan_kernel(const double* __restrict__ edges,
                                                    int* __restrict__ pos,
                                                    int* __restrict__ Karr,
                                                    float* __restrict__ mask_out) {
    int b = blockIdx.x;
    const double* e = edges + ((size_t)b << 14);
    int t = threadIdx.x;
    int lane = t & 63, wid = t >> 6;
    double v[16];
    #pragma unroll
    for (int j = 0; j < 8; ++j) {
        double2 dv = *(const double2*)&e[t * 16 + j * 2];
        v[2 * j] = dv.x; v[2 * j + 1] = dv.y;
    }
    double s = 0.0;
    #pragma unroll
    for (int j = 0; j < 16; ++j) s += v[j];
    #pragma unroll
    for (int off = 32; off > 0; off >>= 1) s += __shfl_xor(s, off);
    __shared__ double wsum[16];
    __shared__ int wcnt[16];
    if (lane == 0) wsum[wid] = s;
    __syncthreads();
    double total = 0.0;
    #pragma unroll
    for (int w = 0; w < 16; ++w) total += wsum[w];
    double mean = total * (1.0 / 16384.0);
    int m[16], cnt = 0;
    #pragma unroll
    for (int j = 0; j < 16; ++j) { m[j] = (v[j] > mean) ? 1 : 0; cnt += m[j]; }
    int incl = cnt;
    #pragma unroll
    for (int off = 1; off < 64; off <<= 1) {
        int up = __shfl_up(incl, off);
        if (lane >= off) incl += up;
    }
    if (lane == 63) wcnt[wid] = incl;
    __syncthreads();
    int woff = 0, Ktot = 0;
    #pragma unroll
    for (int w = 0; w < 16; ++w) { int c = wcnt[w]; Ktot += c; if (w < wid) woff += c; }
    int run = woff + incl - cnt;
    float mf[16]; int pv[16];
    #pragma unroll
    for (int j = 0; j < 16; ++j) {
        pv[j] = m[j] ? run : -1;
        run += m[j];
        mf[j] = m[j] ? 1.0f : 0.0f;
    }
    float* mb = mask_out + ((size_t)b << 14) + t * 16;
    int* pb = pos + ((size_t)b << 14) + t * 16;
    #pragma unroll
    for (int q = 0; q < 4; ++q) {
        nt_store4(&mb[q * 4], mf[4 * q], mf[4 * q + 1], mf[4 * q + 2], mf[4 * q + 3]);
        *(int4*)&pb[q * 4] = make_int4(pv[4 * q], pv[4 * q + 1], pv[4 * q + 2], pv[4 * q + 3]);
    }
    if (t == 0) Karr[b] = Ktot;
}

// ---------------- Kernel 3: fine patch embed + compact scatter + fill ------
// grid (256, 8), 256 threads; 64 fine patches/block; thread = 4 dims of token
__global__ __launch_bounds__(256) void fine_kernel(const float* __restrict__ x,
                                                   const float* __restrict__ wfp,
                                                   const float* __restrict__ bfp,
                                                   const float* __restrict__ temb,
                                                   const int* __restrict__ pos,
                                                   const int* __restrict__ Karr,
                                                   float* __restrict__ out) {
    int b = blockIdx.y;
    int i0 = blockIdx.x * 64;
    int hf = i0 >> 7;
    int wf0 = i0 & 127;
    int t = threadIdx.x;
    int d4 = t & 31;        // float4 lane over dims
    int g = t >> 5;         // 0..7
    __shared__ float smx[4][256];
    float4 wcol[16];
    #pragma unroll
    for (int k = 0; k < 16; ++k) wcol[k] = *(const float4*)&wfp[k * ED + d4 * 4];
    const float* img = x + ((size_t)b * IMH + hf * 4) * IMW + wf0 * 4;
    {
        int r = t >> 6, c4 = t & 63;   // 4 rows x 64 float4
        *(float4*)&smx[r][c4 * 4] = *(const float4*)&img[r * IMW + c4 * 4];
    }
    __syncthreads();
    int K = Karr[b];
    const int* posb = pos + ((size_t)b << 14);
    float4 fill = *(const float4*)&temb[ED + d4 * 4];
    float4 bse = *(const float4*)&bfp[d4 * 4];
    float4 base = make_float4(bse.x + fill.x, bse.y + fill.y, bse.z + fill.z, bse.w + fill.w);
    float* tok = out + ((size_t)b * NTOK + NC) * ED;
    #pragma unroll
    for (int pp = 0; pp < 8; ++pp) {
        int p = g + pp * 8;
        int i = i0 + p;
        int ps = posb[i];
        if (ps >= 0) {
            float4 acc = base;
            #pragma unroll
            for (int r = 0; r < 4; ++r) {
                float4 vv = *(const float4*)&smx[r][p * 4];
                acc.x += vv.x * wcol[4 * r].x + vv.y * wcol[4 * r + 1].x + vv.z * wcol[4 * r + 2].x + vv.w * wcol[4 * r + 3].x;
                acc.y += vv.x * wcol[4 * r].y + vv.y * wcol[4 * r + 1].y + vv.z * wcol[4 * r + 2].y + vv.w * wcol[4 * r + 3].y;
                acc.z += vv.x * wcol[4 * r].z + vv.y * wcol[4 * r + 1].z + vv.z * wcol[4 * r + 2].z + vv.w * wcol[4 * r + 3].z;
                acc.w += vv.x * wcol[4 * r].w + vv.y * wcol[4 * r + 1].w + vv.z * wcol[4 * r + 2].w + vv.w * wcol[4 * r + 3].w;
            }
            nt_store4v(tok + ((size_t)ps * 32 + d4) * 4, acc);
        }
        if (i >= K) {
            nt_store4v(tok + ((size_t)i * 32 + d4) * 4, fill);
        }
    }
}

extern "C" void kernel_launch(void* const* d_in, const int* in_sizes, int n_in,
                              void* d_out, int out_size, void* d_ws, size_t ws_size,
                              hipStream_t stream) {
    const float* x    = (const float*)d_in[0];
    const float* wc   = (const float*)d_in[1];
    const float* bc   = (const float*)d_in[2];
    const float* wfp  = (const float*)d_in[3];
    const float* bfp  = (const float*)d_in[4];
    const float* temb = (const float*)d_in[5];
    float* out = (float*)d_out;

    double* edges = (double*)d_ws;                                  // 1 MiB
    int* pos  = (int*)((char*)d_ws + (size_t)BATCH * NF * sizeof(double));
    int* Karr = (int*)((char*)d_ws + (size_t)BATCH * NF * (sizeof(double) + sizeof(int)));

    float* mask_out = out + (size_t)BATCH * NTOK * ED;

    fused_edge_coarse<<<dim3(2560), 256, 0, stream>>>(x, wc, bc, temb, out, edges);
    scan_kernel<<<dim3(BATCH), 1024, 0, stream>>>(edges, pos, Karr, mask_out);
    fine_kernel<<<dim3(256, BATCH), 256, 0, stream>>>(x, wfp, bfp, temb, pos, Karr, out);
}

// Round 5
// 49.231 us; speedup vs baseline: 1.1818x; 1.0832x over previous
//
#include <hip/hip_runtime.h>

#define IMH 512
#define IMW 512
#define BATCH 8
#define NTOK 20480
#define NC 4096
#define NF 16384
#define ED 128

typedef float vf4 __attribute__((ext_vector_type(4)));

__device__ __forceinline__ void nt_store4(float* p, float a, float b, float c, float d) {
    vf4 v = {a, b, c, d};
    __builtin_nontemporal_store(v, (vf4*)p);
}
__device__ __forceinline__ void nt_store4v(float* p, float4 v) {
    nt_store4(p, v.x, v.y, v.z, v.w);
}

// ---------------- Kernel 1: fused coarse embed + Sobel edge map ------------
// blocks [0,1024): coarse, 32 patches/block, 256 threads, NO LDS:
//   wave = 16 patches x one d-half; patch pixels via wave-uniform scalar loads
// blocks [1024,1536): edge, 64x64 pixel tile -> 16x16 pooled cells (fp64)
__global__ __launch_bounds__(256) void fused_edge_coarse(const float* __restrict__ x,
                                                         const float* __restrict__ wc,
                                                         const float* __restrict__ bc,
                                                         const float* __restrict__ temb,
                                                         float* __restrict__ out,
                                                         double* __restrict__ edges) {
    __shared__ float esm[66][68];
    int blk = blockIdx.x;
    int t = threadIdx.x;
    if (blk < 1024) {
        // ---- coarse role ----
        int b = blk >> 7;                       // 128 blocks per batch
        int pblk = (blk & 127) * 32;            // 32 patches per block
        int wv = __builtin_amdgcn_readfirstlane(t >> 6);  // wave id 0..3 (SGPR)
        int lane = t & 63;
        int h = wv & 1;                         // d-half
        int p0 = pblk + (wv >> 1) * 16;         // 16 patches for this wave
        int d = h * 64 + lane;
        float wcol[64];
        #pragma unroll
        for (int k = 0; k < 64; ++k) wcol[k] = wc[k * ED + d];
        float base = bc[d] + temb[d];
        // p0 is a multiple of 16 -> all 16 patches share one patch-row (64/row)
        const float* img = x + ((size_t)b * IMH + (p0 >> 6) * 8) * IMW + (p0 & 63) * 8;
        float* dst = out + ((size_t)b * NTOK + p0) * ED + d;
        #pragma unroll
        for (int p = 0; p < 16; ++p) {
            const float* pimg = img + p * 8;    // wave-uniform -> scalar loads
            float acc = base;
            #pragma unroll
            for (int r = 0; r < 8; ++r) {
                const float* rp = pimg + r * IMW;
                acc += rp[0] * wcol[r * 8 + 0] + rp[1] * wcol[r * 8 + 1]
                     + rp[2] * wcol[r * 8 + 2] + rp[3] * wcol[r * 8 + 3]
                     + rp[4] * wcol[r * 8 + 4] + rp[5] * wcol[r * 8 + 5]
                     + rp[6] * wcol[r * 8 + 6] + rp[7] * wcol[r * 8 + 7];
            }
            __builtin_nontemporal_store(acc, dst + (size_t)p * ED);
        }
    } else {
        // ---- edge role (identical fp64 math to round-1 passing version) ----
        int blk2 = blk - 1024;
        int b = blk2 >> 6;
        int tile = blk2 & 63;
        int ty0 = (tile >> 3) * 64;
        int tx0 = (tile & 7) * 64;
        const float* img = x + (size_t)b * (IMH * IMW);
        for (int idx = t; idx < 66 * 66; idx += 256) {
            int r = idx / 66, c = idx - r * 66;
            int gy = ty0 - 1 + r, gx = tx0 - 1 + c;
            float v = 0.f;
            if (gy >= 0 && gy < IMH && gx >= 0 && gx < IMW) v = img[gy * IMW + gx];
            esm[r][c] = v;
        }
        __syncthreads();
        int cy = t >> 4, cx = t & 15;
        double acc = 0.0;
        #pragma unroll
        for (int dy = 0; dy < 4; ++dy) {
            int py = cy * 4 + dy + 1;
            #pragma unroll
            for (int dx = 0; dx < 4; ++dx) {
                int px = cx * 4 + dx + 1;
                double a00 = (double)esm[py - 1][px - 1];
                double a01 = (double)esm[py - 1][px];
                double a02 = (double)esm[py - 1][px + 1];
                double a10 = (double)esm[py][px - 1];
                double a12 = (double)esm[py][px + 1];
                double a20 = (double)esm[py + 1][px - 1];
                double a21 = (double)esm[py + 1][px];
                double a22 = (double)esm[py + 1][px + 1];
                double sx = (a02 + 2.0 * a12 + a22) - (a00 + 2.0 * a10 + a20);
                double sy = (a20 + 2.0 * a21 + a22) - (a00 + 2.0 * a01 + a02);
                acc += sqrt(sx * sx + sy * sy);
            }
        }
        int gy = (ty0 >> 2) + cy;
        int gx = (tx0 >> 2) + cx;
        edges[((size_t)b << 14) + gy * 128 + gx] = acc * (1.0 / 16.0);
    }
}

// ---------------- Kernel 2: per-batch mean, mask, prefix scan --------------
// one block per batch, 1024 threads, 16 elements/thread, 2 barriers
__global__ __launch_bounds__(1024) void scan_kernel(const double* __restrict__ edges,
                                                    int* __restrict__ pos,
                                                    int* __restrict__ Karr,
                                                    float* __restrict__ mask_out) {
    int b = blockIdx.x;
    const double* e = edges + ((size_t)b << 14);
    int t = threadIdx.x;
    int lane = t & 63, wid = t >> 6;
    double v[16];
    #pragma unroll
    for (int j = 0; j < 8; ++j) {
        double2 dv = *(const double2*)&e[t * 16 + j * 2];
        v[2 * j] = dv.x; v[2 * j + 1] = dv.y;
    }
    double s = 0.0;
    #pragma unroll
    for (int j = 0; j < 16; ++j) s += v[j];
    #pragma unroll
    for (int off = 32; off > 0; off >>= 1) s += __shfl_xor(s, off);
    __shared__ double wsum[16];
    __shared__ int wcnt[16];
    if (lane == 0) wsum[wid] = s;
    __syncthreads();
    double total = 0.0;
    #pragma unroll
    for (int w = 0; w < 16; ++w) total += wsum[w];
    double mean = total * (1.0 / 16384.0);
    int m[16], cnt = 0;
    #pragma unroll
    for (int j = 0; j < 16; ++j) { m[j] = (v[j] > mean) ? 1 : 0; cnt += m[j]; }
    int incl = cnt;
    #pragma unroll
    for (int off = 1; off < 64; off <<= 1) {
        int up = __shfl_up(incl, off);
        if (lane >= off) incl += up;
    }
    if (lane == 63) wcnt[wid] = incl;
    __syncthreads();
    int woff = 0, Ktot = 0;
    #pragma unroll
    for (int w = 0; w < 16; ++w) { int c = wcnt[w]; Ktot += c; if (w < wid) woff += c; }
    int run = woff + incl - cnt;
    float mf[16]; int pv[16];
    #pragma unroll
    for (int j = 0; j < 16; ++j) {
        pv[j] = m[j] ? run : -1;
        run += m[j];
        mf[j] = m[j] ? 1.0f : 0.0f;
    }
    float* mb = mask_out + ((size_t)b << 14) + t * 16;
    int* pb = pos + ((size_t)b << 14) + t * 16;
    #pragma unroll
    for (int q = 0; q < 4; ++q) {
        nt_store4(&mb[q * 4], mf[4 * q], mf[4 * q + 1], mf[4 * q + 2], mf[4 * q + 3]);
        *(int4*)&pb[q * 4] = make_int4(pv[4 * q], pv[4 * q + 1], pv[4 * q + 2], pv[4 * q + 3]);
    }
    if (t == 0) Karr[b] = Ktot;
}

// ---------------- Kernel 3: fine patch embed + compact scatter + fill ------
// grid (256, 8), 256 threads; 64 fine patches/block; thread = 4 dims of token
__global__ __launch_bounds__(256) void fine_kernel(const float* __restrict__ x,
                                                   const float* __restrict__ wfp,
                                                   const float* __restrict__ bfp,
                                                   const float* __restrict__ temb,
                                                   const int* __restrict__ pos,
                                                   const int* __restrict__ Karr,
                                                   float* __restrict__ out) {
    int b = blockIdx.y;
    int i0 = blockIdx.x * 64;
    int hf = i0 >> 7;
    int wf0 = i0 & 127;
    int t = threadIdx.x;
    int d4 = t & 31;        // float4 lane over dims
    int g = t >> 5;         // 0..7
    __shared__ float smx[4][256];
    float4 wcol[16];
    #pragma unroll
    for (int k = 0; k < 16; ++k) wcol[k] = *(const float4*)&wfp[k * ED + d4 * 4];
    const float* img = x + ((size_t)b * IMH + hf * 4) * IMW + wf0 * 4;
    {
        int r = t >> 6, c4 = t & 63;   // 4 rows x 64 float4
        *(float4*)&smx[r][c4 * 4] = *(const float4*)&img[r * IMW + c4 * 4];
    }
    __syncthreads();
    int K = Karr[b];
    const int* posb = pos + ((size_t)b << 14);
    float4 fill = *(const float4*)&temb[ED + d4 * 4];
    float4 bse = *(const float4*)&bfp[d4 * 4];
    float4 base = make_float4(bse.x + fill.x, bse.y + fill.y, bse.z + fill.z, bse.w + fill.w);
    float* tok = out + ((size_t)b * NTOK + NC) * ED;
    #pragma unroll
    for (int pp = 0; pp < 8; ++pp) {
        int p = g + pp * 8;
        int i = i0 + p;
        int ps = posb[i];
        if (ps >= 0) {
            float4 acc = base;
            #pragma unroll
            for (int r = 0; r < 4; ++r) {
                float4 vv = *(const float4*)&smx[r][p * 4];
                acc.x += vv.x * wcol[4 * r].x + vv.y * wcol[4 * r + 1].x + vv.z * wcol[4 * r + 2].x + vv.w * wcol[4 * r + 3].x;
                acc.y += vv.x * wcol[4 * r].y + vv.y * wcol[4 * r + 1].y + vv.z * wcol[4 * r + 2].y + vv.w * wcol[4 * r + 3].y;
                acc.z += vv.x * wcol[4 * r].z + vv.y * wcol[4 * r + 1].z + vv.z * wcol[4 * r + 2].z + vv.w * wcol[4 * r + 3].z;
                acc.w += vv.x * wcol[4 * r].w + vv.y * wcol[4 * r + 1].w + vv.z * wcol[4 * r + 2].w + vv.w * wcol[4 * r + 3].w;
            }
            nt_store4v(tok + ((size_t)ps * 32 + d4) * 4, acc);
        }
        if (i >= K) {
            nt_store4v(tok + ((size_t)i * 32 + d4) * 4, fill);
        }
    }
}

extern "C" void kernel_launch(void* const* d_in, const int* in_sizes, int n_in,
                              void* d_out, int out_size, void* d_ws, size_t ws_size,
                              hipStream_t stream) {
    const float* x    = (const float*)d_in[0];
    const float* wc   = (const float*)d_in[1];
    const float* bc   = (const float*)d_in[2];
    const float* wfp  = (const float*)d_in[3];
    const float* bfp  = (const float*)d_in[4];
    const float* temb = (const float*)d_in[5];
    float* out = (float*)d_out;

    double* edges = (double*)d_ws;                                  // 1 MiB
    int* pos  = (int*)((char*)d_ws + (size_t)BATCH * NF * sizeof(double));
    int* Karr = (int*)((char*)d_ws + (size_t)BATCH * NF * (sizeof(double) + sizeof(int)));

    float* mask_out = out + (size_t)BATCH * NTOK * ED;

    fused_edge_coarse<<<dim3(1536), 256, 0, stream>>>(x, wc, bc, temb, out, edges);
    scan_kernel<<<dim3(BATCH), 1024, 0, stream>>>(edges, pos, Karr, mask_out);
    fine_kernel<<<dim3(256, BATCH), 256, 0, stream>>>(x, wfp, bfp, temb, pos, Karr, out);
}